// Round 7
// baseline (1551.473 us; speedup 1.0000x reference)
//
#include <hip/hip_runtime.h>
#include <hip/hip_bf16.h>
#include <stdint.h>

// B=8192, D_IN=1024, D_HID=4096, D_OUT=1024, E=8
#define BB 8192
#define DIN 1024
#define DHID 4096
#define DOUT 1024
#define NEXP 8
#define GH_N 2048  // D_HID/2

typedef __attribute__((ext_vector_type(8))) __bf16 bf16x8;
typedef __attribute__((ext_vector_type(4))) float f32x4;

__device__ inline unsigned short f2bf(float f) {
  unsigned u = __builtin_bit_cast(unsigned, f);
  u = (u + 0x7FFFu + ((u >> 16) & 1u)) >> 16;
  return (unsigned short)u;
}
__device__ inline float b2f(unsigned short s) {
  return __builtin_bit_cast(float, (unsigned)s << 16);
}

// ---------------- elementwise f32 -> bf16 ----------------
__global__ void cvt_f32_bf16(const float* __restrict__ in,
                             unsigned short* __restrict__ out, int n4) {
  int i = blockIdx.x * blockDim.x + threadIdx.x;
  if (i >= n4) return;
  float4 v = ((const float4*)in)[i];
  ushort4 o;
  o.x = f2bf(v.x); o.y = f2bf(v.y); o.z = f2bf(v.z); o.w = f2bf(v.w);
  ((ushort4*)out)[i] = o;
}

// ------------- transpose + convert, 64x64 tile: in[R][C] f32 -> out[C][R] bf16
__device__ inline void tr_tile64(const float* __restrict__ in,
                                 unsigned short* __restrict__ out, int R, int C,
                                 int bx, int by) {
  __shared__ float tile[64][65];
  const int c0 = bx * 64, r0 = by * 64;
  const int tx = threadIdx.x & 63, ty = threadIdx.x >> 6;  // ty 0..3
#pragma unroll
  for (int i = 0; i < 16; ++i) {
    int r = i * 4 + ty;
    tile[r][tx] = in[(size_t)(r0 + r) * C + c0 + tx];
  }
  __syncthreads();
#pragma unroll
  for (int i = 0; i < 16; ++i) {
    int r = i * 4 + ty;
    out[(size_t)(c0 + r) * R + r0 + tx] = f2bf(tile[tx][r]);
  }
}

__global__ void transpose_cvt64(const float* __restrict__ in,
                                unsigned short* __restrict__ out, int R, int C) {
  tr_tile64(in, out, R, C, blockIdx.x, blockIdx.y);
}

// fused per-expert: W1 [1024][4096]->w1T[4096][1024], W2 [4096][1024]->w2T[1024][4096]
__global__ void transpose_cvt2(const float* __restrict__ w1,
                               unsigned short* __restrict__ w1T,
                               const float* __restrict__ w2,
                               unsigned short* __restrict__ w2T) {
  int b = blockIdx.x;
  if (b < 1024) {
    tr_tile64(w1, w1T, DIN, DHID, b & 63, b >> 6);   // bx 0..63, by 0..15
  } else {
    b -= 1024;
    tr_tile64(w2, w2T, DHID, DOUT, b & 15, b >> 4);  // bx 0..15, by 0..63
  }
}

// ---------------- async global->LDS 16B ----------------
__device__ inline void gload16(const void* g, void* l) {
  __builtin_amdgcn_global_load_lds(
      (const __attribute__((address_space(1))) void*)g,
      (__attribute__((address_space(3))) void*)l, 16, 0, 0);
}

template <int N>
__device__ inline void waitv() {
  if constexpr (N == 0) asm volatile("s_waitcnt vmcnt(0)" ::: "memory");
  else if constexpr (N == 2) asm volatile("s_waitcnt vmcnt(2)" ::: "memory");
  else if constexpr (N == 4) asm volatile("s_waitcnt vmcnt(4)" ::: "memory");
  else asm volatile("s_waitcnt vmcnt(0)" ::: "memory");
}
__device__ inline void waitlgkm0() {
  asm volatile("s_waitcnt lgkmcnt(0)" ::: "memory");
  __builtin_amdgcn_sched_barrier(0);
}
__device__ inline bf16x8 ldr(const char* p) { return *(const bf16x8*)p; }

// ---------------- unified fat GEMM core: 256x256 tile, 4-phase, BK=64 ------
// C = A[8192,K]*Bt[N,K]^T. 8 waves (2M x 4N), 2 LDS buffers, counted vmcnt.
// epi 0: outb = bf16(relu(acc+bias[col]))
// epi 3: split-K x2 (ks=swz&1, k-offset ks*K) + atomic gated add:
//        outC[row][col] += gates[row*8+eidx]*acc   (bias pre-folded by init_c)
struct GArgs {
  const unsigned short* A;
  const unsigned short* Bt;
  int lda, ldb, N, K;
  const float* bias;
  unsigned short* outb;
  float* outf;
  const float* gates;
  int eidx, epi, nb;
};

__global__ __launch_bounds__(512, 2)
void gemmU(GArgs g) {
  __shared__ char lds[131072];
  char* Als = lds;
  char* Bls = lds + 65536;
  constexpr int ABYTES = 32768, BBYTES = 32768;
  const int t = threadIdx.x;
  const int lane = t & 63;
  const int wid = t >> 6;
  const int wm = wid >> 2;
  const int wn = wid & 3;
  const int l15 = lane & 15, lg = lane >> 4;

  // bijective XCD swizzle (nb % 8 == 0 for all roles)
  const int nb = g.nb;
  const int local = blockIdx.x;
  const int swz = (local & 7) * (nb >> 3) + (local >> 3);
  int ks = 0, tid = swz;
  if (g.epi == 3) { ks = swz & 1; tid = swz >> 1; }
  const int nbn = g.N >> 8;
  const int bn = tid % nbn, bm = tid / nbn;
  const int m0 = bm * 256, n0 = bn * 256;
  const int kbase = ks * g.K;

  // stage source pointers (XOR chunk swizzle, involution shared with reads)
  const int prow = t >> 3;
  const int cOff = ((t & 7) ^ (prow & 7)) * 8;
  const unsigned short* aP[4];
  const unsigned short* bP[4];
#pragma unroll
  for (int u = 0; u < 4; ++u) {
    int p = u * 64 + prow;
    int ga = ((p >> 6) & 1) * 128 + ((p >> 7) & 1) * 64 + (p & 63);
    aP[u] = g.A + (size_t)(m0 + ga) * g.lda + kbase + cOff;
    int gb = ((p >> 5) & 3) * 64 + ((p >> 7) & 1) * 32 + (p & 31);
    bP[u] = g.Bt + (size_t)(n0 + gb) * g.ldb + kbase + cOff;
  }
  const int ldst = t * 16;

  // LDS read bases
  const int slot0 = ((lg) ^ (l15 & 7)) * 16;
  const int slot1 = ((4 + lg) ^ (l15 & 7)) * 16;
  const int aRB0 = (wm * 64 + l15) * 128;
  const int aRB1 = (128 + wm * 64 + l15) * 128;
  const int bCB0 = (wn * 32 + l15) * 128;
  const int bCB1 = (128 + wn * 32 + l15) * 128;

  f32x4 acc[8][4];
  const f32x4 zero = {0.f, 0.f, 0.f, 0.f};
#pragma unroll
  for (int i = 0; i < 8; ++i)
#pragma unroll
    for (int j = 0; j < 4; ++j) acc[i][j] = zero;

  bf16x8 ar[4][2], bc0[2][2], bc1[2][2];
  const int NT = g.K >> 6;

  // prologue: stage tile 0 in positional order, retire ph0-set
  gload16(bP[0], Bls + 0 * 8192 + ldst);
  gload16(bP[1], Bls + 1 * 8192 + ldst);
  gload16(aP[0], Als + 0 * 8192 + ldst);
  gload16(aP[1], Als + 1 * 8192 + ldst);
  gload16(bP[2], Bls + 2 * 8192 + ldst);
  gload16(bP[3], Bls + 3 * 8192 + ldst);
  gload16(aP[2], Als + 2 * 8192 + ldst);
  gload16(aP[3], Als + 3 * 8192 + ldst);
  waitv<4>();
  __builtin_amdgcn_s_barrier();

  for (int T = 0; T < NT; ++T) {
    const int buf = T & 1;
    const char* Ab = Als + buf * ABYTES;
    const char* Bb = Bls + buf * BBYTES;
    char* An = Als + (buf ^ 1) * ABYTES;
    char* Bn = Bls + (buf ^ 1) * BBYTES;
    const bool stg = (T + 1 < NT);
    const int kn = (T + 1) << 6;

    // ph0: read A rh0 + B ch0; stage B0,B1; mfma (rh0, cols 0-1)
#pragma unroll
    for (int f = 0; f < 4; ++f) {
      ar[f][0] = ldr(Ab + aRB0 + f * 2048 + slot0);
      ar[f][1] = ldr(Ab + aRB0 + f * 2048 + slot1);
    }
#pragma unroll
    for (int c = 0; c < 2; ++c) {
      bc0[c][0] = ldr(Bb + bCB0 + c * 2048 + slot0);
      bc0[c][1] = ldr(Bb + bCB0 + c * 2048 + slot1);
    }
    if (stg) {
      gload16(bP[0] + kn, Bn + 0 * 8192 + ldst);
      gload16(bP[1] + kn, Bn + 1 * 8192 + ldst);
    }
    __builtin_amdgcn_s_barrier();
    waitlgkm0();
    __builtin_amdgcn_s_setprio(1);
#pragma unroll
    for (int ksl = 0; ksl < 2; ++ksl)
#pragma unroll
      for (int f = 0; f < 4; ++f)
#pragma unroll
        for (int c = 0; c < 2; ++c)
          acc[f][c] = __builtin_amdgcn_mfma_f32_16x16x32_bf16(
              ar[f][ksl], bc0[c][ksl], acc[f][c], 0, 0, 0);
    __builtin_amdgcn_s_setprio(0);
    if (stg) waitv<4>(); else waitv<2>();
    __builtin_amdgcn_s_barrier();

    // ph1: read B ch1; stage A0,A1; mfma (rh0, cols 2-3)
#pragma unroll
    for (int c = 0; c < 2; ++c) {
      bc1[c][0] = ldr(Bb + bCB1 + c * 2048 + slot0);
      bc1[c][1] = ldr(Bb + bCB1 + c * 2048 + slot1);
    }
    if (stg) {
      gload16(aP[0] + kn, An + 0 * 8192 + ldst);
      gload16(aP[1] + kn, An + 1 * 8192 + ldst);
    }
    __builtin_amdgcn_s_barrier();
    waitlgkm0();
    __builtin_amdgcn_s_setprio(1);
#pragma unroll
    for (int ksl = 0; ksl < 2; ++ksl)
#pragma unroll
      for (int f = 0; f < 4; ++f)
#pragma unroll
        for (int c = 0; c < 2; ++c)
          acc[f][2 + c] = __builtin_amdgcn_mfma_f32_16x16x32_bf16(
              ar[f][ksl], bc1[c][ksl], acc[f][2 + c], 0, 0, 0);
    __builtin_amdgcn_s_setprio(0);
    if (stg) waitv<4>(); else waitv<0>();
    __builtin_amdgcn_s_barrier();

    // ph2: read A rh1; stage B2,B3; mfma (rh1, cols 2-3)
#pragma unroll
    for (int f = 0; f < 4; ++f) {
      ar[f][0] = ldr(Ab + aRB1 + f * 2048 + slot0);
      ar[f][1] = ldr(Ab + aRB1 + f * 2048 + slot1);
    }
    if (stg) {
      gload16(bP[2] + kn, Bn + 2 * 8192 + ldst);
      gload16(bP[3] + kn, Bn + 3 * 8192 + ldst);
    }
    __builtin_amdgcn_s_barrier();
    waitlgkm0();
    __builtin_amdgcn_s_setprio(1);
#pragma unroll
    for (int ksl = 0; ksl < 2; ++ksl)
#pragma unroll
      for (int f = 0; f < 4; ++f)
#pragma unroll
        for (int c = 0; c < 2; ++c)
          acc[4 + f][2 + c] = __builtin_amdgcn_mfma_f32_16x16x32_bf16(
              ar[f][ksl], bc1[c][ksl], acc[4 + f][2 + c], 0, 0, 0);
    __builtin_amdgcn_s_setprio(0);
    __builtin_amdgcn_s_barrier();

    // ph3: no ds_reads; stage A2,A3; mfma (rh1, cols 0-1)
    if (stg) {
      gload16(aP[2] + kn, An + 2 * 8192 + ldst);
      gload16(aP[3] + kn, An + 3 * 8192 + ldst);
    }
    __builtin_amdgcn_s_barrier();
    __builtin_amdgcn_s_setprio(1);
#pragma unroll
    for (int ksl = 0; ksl < 2; ++ksl)
#pragma unroll
      for (int f = 0; f < 4; ++f)
#pragma unroll
        for (int c = 0; c < 2; ++c)
          acc[4 + f][c] = __builtin_amdgcn_mfma_f32_16x16x32_bf16(
              ar[f][ksl], bc0[c][ksl], acc[4 + f][c], 0, 0, 0);
    __builtin_amdgcn_s_setprio(0);
    if (stg) waitv<4>();
    __builtin_amdgcn_s_barrier();
  }

  // epilogue: D row = lg*4 + reg (within 16), col = l15 (m89-verified)
  const int rb = m0 + wm * 128 + (lg << 2);
  const int cb = n0 + wn * 64 + l15;
  const int N = g.N;
  if (g.epi == 0) {
#pragma unroll
    for (int fg = 0; fg < 8; ++fg) {
#pragma unroll
      for (int j = 0; j < 4; ++j) {
        int col = cb + j * 16;
        float bv = g.bias[col];
#pragma unroll
        for (int r = 0; r < 4; ++r) {
          int row = rb + fg * 16 + r;
          float v = acc[fg][j][r] + bv;
          g.outb[(size_t)row * N + col] = f2bf(fmaxf(v, 0.f));
        }
      }
    }
  } else {  // epi 3: atomic gated accumulate (bias handled by init_c)
#pragma unroll
    for (int fg = 0; fg < 8; ++fg) {
      float gv[4];
#pragma unroll
      for (int r = 0; r < 4; ++r)
        gv[r] = g.gates[(size_t)(rb + fg * 16 + r) * NEXP + g.eidx];
#pragma unroll
      for (int j = 0; j < 4; ++j) {
        int col = cb + j * 16;
#pragma unroll
        for (int r = 0; r < 4; ++r) {
          size_t o = (size_t)(rb + fg * 16 + r) * N + col;
          __hip_atomic_fetch_add(&g.outf[o], acc[fg][j][r] * gv[r],
                                 __ATOMIC_RELAXED, __HIP_MEMORY_SCOPE_AGENT);
        }
      }
    }
  }
}

// ---------------- outC init: outC[r][c] = sum_e gat[r][e]*eb2[e][c] -------
__global__ void init_c(const float* __restrict__ gat,
                       const float* __restrict__ eb2,
                       float* __restrict__ outC) {
  const int r = blockIdx.x;         // 0..8191
  const int c4 = threadIdx.x;       // 0..255 (f4 over 1024 cols)
  float g[8];
#pragma unroll
  for (int e = 0; e < 8; ++e) g[e] = gat[(size_t)r * NEXP + e];
  float4 o = {0.f, 0.f, 0.f, 0.f};
#pragma unroll
  for (int e = 0; e < 8; ++e) {
    float4 b = ((const float4*)(eb2 + (size_t)e * DOUT))[c4];
    o.x += g[e] * b.x; o.y += g[e] * b.y;
    o.z += g[e] * b.z; o.w += g[e] * b.w;
  }
  ((float4*)(outC + (size_t)r * DOUT))[c4] = o;
}

// ---------------- gating head ----------------
__global__ __launch_bounds__(512)
void gating_head2(const unsigned short* __restrict__ gh,
                  const float* __restrict__ gW2,
                  const float* __restrict__ gb2,
                  float* __restrict__ gws,
                  float* __restrict__ g1,
                  float* __restrict__ g2) {
  __shared__ float wT[8][2048];
  const int t = threadIdx.x;
  for (int idx = t; idx < 16384; idx += 512) {
    wT[idx & 7][idx >> 3] = gW2[idx];
  }
  __syncthreads();
  const int wid = t >> 6, lane = t & 63;
  const int row = blockIdx.x * 8 + wid;
  const unsigned short* ghr = gh + (size_t)row * 2048;
  float s[8] = {0.f, 0.f, 0.f, 0.f, 0.f, 0.f, 0.f, 0.f};
#pragma unroll
  for (int j = 0; j < 8; ++j) {
    int k4 = lane + 64 * j;
    ushort4 hv = ((const ushort4*)ghr)[k4];
    float h0 = b2f(hv.x), h1 = b2f(hv.y), h2 = b2f(hv.z), h3 = b2f(hv.w);
#pragma unroll
    for (int e = 0; e < 8; ++e) {
      float4 w = ((const float4*)&wT[e][0])[k4];
      s[e] += h0 * w.x + h1 * w.y + h2 * w.z + h3 * w.w;
    }
  }
#pragma unroll
  for (int e = 0; e < 8; ++e)
#pragma unroll
    for (int off = 1; off < 64; off <<= 1) s[e] += __shfl_xor(s[e], off, 64);
  if (lane == 0) {
    float l[8], m = -1e30f;
#pragma unroll
    for (int e = 0; e < 8; ++e) {
      l[e] = s[e] + gb2[e];
      m = fmaxf(m, l[e]);
    }
    float sum = 0.f;
#pragma unroll
    for (int e = 0; e < 8; ++e) {
      l[e] = expf(l[e] - m);
      sum += l[e];
    }
    float inv = 1.f / sum;
#pragma unroll
    for (int e = 0; e < 8; ++e) {
      float gv = l[e] * inv;
      gws[(size_t)row * 8 + e] = gv;
      g1[(size_t)row * 8 + e] = gv;
      g2[(size_t)row * 8 + e] = gv;
    }
  }
}

extern "C" void kernel_launch(void* const* d_in, const int* in_sizes, int n_in,
                              void* d_out, int out_size, void* d_ws,
                              size_t ws_size, hipStream_t stream) {
  (void)in_sizes; (void)n_in; (void)out_size; (void)ws_size;
  const float* x   = (const float*)d_in[0];
  const float* gW1 = (const float*)d_in[1];
  const float* gb1 = (const float*)d_in[2];
  const float* gW2 = (const float*)d_in[3];
  const float* gb2 = (const float*)d_in[4];
  const float* eW1 = (const float*)d_in[5];
  const float* eb1 = (const float*)d_in[6];
  const float* eW2 = (const float*)d_in[7];
  const float* eb2 = (const float*)d_in[8];

  float* outC  = (float*)d_out;                       // [8192,1024]
  float* outG1 = outC + (size_t)BB * DOUT;            // [8192,8]
  float* outG2 = outG1 + (size_t)BB * NEXP;           // [8192,8]

  char* ws = (char*)d_ws;
  // layout: 100,925,440 B total (well under proven capacity)
  unsigned short* xb   = (unsigned short*)(ws);                 // 16 MB
  float*          gat  = (float*)(ws + 16777216);               // 256 KB
  unsigned short* w1T  = (unsigned short*)(ws + 17039360);      // 8 MB
  unsigned short* w2T  = (unsigned short*)(ws + 25427968);      // 8 MB
  unsigned short* hbuf = (unsigned short*)(ws + 33816576);      // 64 MB
  unsigned short* gh   = hbuf;                  // pre-loop alias (32 MB)
  unsigned short* gW1T = w1T;                   // pre-loop alias (4 MB)

  // x -> bf16
  cvt_f32_bf16<<<(BB * DIN / 4) / 256, 256, 0, stream>>>(x, xb, BB * DIN / 4);
  // gW1 [1024][2048] -> gW1T [2048][1024] bf16   (32x16 64-tiles)
  transpose_cvt64<<<dim3(GH_N / 64, DIN / 64), 256, 0, stream>>>(gW1, gW1T, DIN, GH_N);
  // gating GEMM: gh = relu(x @ gW1 + gb1)   grid 32*8=256 (full chip)
  {
    GArgs a{xb, gW1T, DIN, DIN, GH_N, DIN, gb1, gh, nullptr, nullptr, 0, 0, 256};
    gemmU<<<256, 512, 0, stream>>>(a);
  }
  gating_head2<<<BB / 8, 512, 0, stream>>>(gh, gW2, gb2, gat, outG1, outG2);
  // outC = sum_e gat*eb2 (bias base for atomic accumulation)
  init_c<<<BB, 256, 0, stream>>>(gat, eb2, outC);

  for (int e = 0; e < NEXP; ++e) {
    // transpose both expert weight matrices (2048 64-tiles)
    transpose_cvt2<<<2048, 256, 0, stream>>>(
        eW1 + (size_t)e * DIN * DHID, w1T, eW2 + (size_t)e * DHID * DOUT, w2T);
    // G1: h = relu(x @ eW1_e + eb1_e)   grid 32*16=512 (2 exact rounds)
    {
      GArgs a{xb, w1T, DIN, DIN, DHID, DIN, eb1 + (size_t)e * DHID,
              hbuf, nullptr, nullptr, 0, 0, 512};
      gemmU<<<512, 512, 0, stream>>>(a);
    }
    // G2 split-K x2: outC += gat[:,e]*(h @ eW2_e)   grid 32*4*2=256 (1 round)
    {
      GArgs a{hbuf, w2T, DHID, DHID, DOUT, DHID / 2, nullptr, nullptr,
              outC, gat, e, 3, 256};
      gemmU<<<256, 512, 0, stream>>>(a);
    }
  }
}

// Round 8
// 1342.793 us; speedup vs baseline: 1.1554x; 1.1554x over previous
//
#include <hip/hip_runtime.h>
#include <hip/hip_bf16.h>
#include <stdint.h>

// B=8192, D_IN=1024, D_HID=4096, D_OUT=1024, E=8
#define BB 8192
#define DIN 1024
#define DHID 4096
#define DOUT 1024
#define NEXP 8
#define GH_N 2048  // D_HID/2

typedef __attribute__((ext_vector_type(8))) __bf16 bf16x8;
typedef __attribute__((ext_vector_type(4))) float f32x4;

__device__ inline unsigned short f2bf(float f) {
  unsigned u = __builtin_bit_cast(unsigned, f);
  u = (u + 0x7FFFu + ((u >> 16) & 1u)) >> 16;
  return (unsigned short)u;
}
__device__ inline float b2f(unsigned short s) {
  return __builtin_bit_cast(float, (unsigned)s << 16);
}

// ---------------- elementwise f32 -> bf16 ----------------
__global__ void cvt_f32_bf16(const float* __restrict__ in,
                             unsigned short* __restrict__ out, int n4) {
  int i = blockIdx.x * blockDim.x + threadIdx.x;
  if (i >= n4) return;
  float4 v = ((const float4*)in)[i];
  ushort4 o;
  o.x = f2bf(v.x); o.y = f2bf(v.y); o.z = f2bf(v.z); o.w = f2bf(v.w);
  ((ushort4*)out)[i] = o;
}

// ------------- transpose + convert, 64x64 tile: in[R][C] f32 -> out[C][R] bf16
__device__ inline void tr_tile64(const float* __restrict__ in,
                                 unsigned short* __restrict__ out, int R, int C,
                                 int bx, int by) {
  __shared__ float tile[64][65];
  const int c0 = bx * 64, r0 = by * 64;
  const int tx = threadIdx.x & 63, ty = threadIdx.x >> 6;  // ty 0..3
#pragma unroll
  for (int i = 0; i < 16; ++i) {
    int r = i * 4 + ty;
    tile[r][tx] = in[(size_t)(r0 + r) * C + c0 + tx];
  }
  __syncthreads();
#pragma unroll
  for (int i = 0; i < 16; ++i) {
    int r = i * 4 + ty;
    out[(size_t)(c0 + r) * R + r0 + tx] = f2bf(tile[tx][r]);
  }
}

__global__ void transpose_cvt64(const float* __restrict__ in,
                                unsigned short* __restrict__ out, int R, int C) {
  tr_tile64(in, out, R, C, blockIdx.x, blockIdx.y);
}

// fused per-expert: W1 [1024][4096]->w1T[4096][1024], W2 [4096][1024]->w2T[1024][4096]
__global__ void transpose_cvt2(const float* __restrict__ w1,
                               unsigned short* __restrict__ w1T,
                               const float* __restrict__ w2,
                               unsigned short* __restrict__ w2T) {
  int b = blockIdx.x;
  if (b < 1024) {
    tr_tile64(w1, w1T, DIN, DHID, b & 63, b >> 6);
  } else {
    b -= 1024;
    tr_tile64(w2, w2T, DHID, DOUT, b & 15, b >> 4);
  }
}

// ---------------- async global->LDS 16B ----------------
__device__ inline void gload16(const void* g, void* l) {
  __builtin_amdgcn_global_load_lds(
      (const __attribute__((address_space(1))) void*)g,
      (__attribute__((address_space(3))) void*)l, 16, 0, 0);
}

template <int N>
__device__ inline void waitv() {
  if constexpr (N == 0) asm volatile("s_waitcnt vmcnt(0)" ::: "memory");
  else if constexpr (N == 2) asm volatile("s_waitcnt vmcnt(2)" ::: "memory");
  else if constexpr (N == 4) asm volatile("s_waitcnt vmcnt(4)" ::: "memory");
  else if constexpr (N == 6) asm volatile("s_waitcnt vmcnt(6)" ::: "memory");
  else asm volatile("s_waitcnt vmcnt(0)" ::: "memory");
}
__device__ inline void waitlgkm0() {
  asm volatile("s_waitcnt lgkmcnt(0)" ::: "memory");
  __builtin_amdgcn_sched_barrier(0);
}
__device__ inline bf16x8 ldr(const char* p) { return *(const bf16x8*)p; }

// ---------------- gemmU: 256x256 fat 4-phase (proven ~1270 TF) -------------
// C = A[8192,K]*Bt[N,K]^T, epi: outb = bf16(relu(acc+bias[col]))
struct GArgs {
  const unsigned short* A;
  const unsigned short* Bt;
  int lda, ldb, N, K;
  const float* bias;
  unsigned short* outb;
  int nb;
};

__global__ __launch_bounds__(512, 2)
void gemmU(GArgs g) {
  __shared__ char lds[131072];
  char* Als = lds;
  char* Bls = lds + 65536;
  constexpr int ABYTES = 32768, BBYTES = 32768;
  const int t = threadIdx.x;
  const int lane = t & 63;
  const int wid = t >> 6;
  const int wm = wid >> 2;
  const int wn = wid & 3;
  const int l15 = lane & 15, lg = lane >> 4;

  const int nb = g.nb;
  const int local = blockIdx.x;
  const int swz = (local & 7) * (nb >> 3) + (local >> 3);
  const int nbn = g.N >> 8;
  const int bn = swz % nbn, bm = swz / nbn;
  const int m0 = bm * 256, n0 = bn * 256;

  const int prow = t >> 3;
  const int cOff = ((t & 7) ^ (prow & 7)) * 8;
  const unsigned short* aP[4];
  const unsigned short* bP[4];
#pragma unroll
  for (int u = 0; u < 4; ++u) {
    int p = u * 64 + prow;
    int ga = ((p >> 6) & 1) * 128 + ((p >> 7) & 1) * 64 + (p & 63);
    aP[u] = g.A + (size_t)(m0 + ga) * g.lda + cOff;
    int gb = ((p >> 5) & 3) * 64 + ((p >> 7) & 1) * 32 + (p & 31);
    bP[u] = g.Bt + (size_t)(n0 + gb) * g.ldb + cOff;
  }
  const int ldst = t * 16;

  const int slot0 = ((lg) ^ (l15 & 7)) * 16;
  const int slot1 = ((4 + lg) ^ (l15 & 7)) * 16;
  const int aRB0 = (wm * 64 + l15) * 128;
  const int aRB1 = (128 + wm * 64 + l15) * 128;
  const int bCB0 = (wn * 32 + l15) * 128;
  const int bCB1 = (128 + wn * 32 + l15) * 128;

  f32x4 acc[8][4];
  const f32x4 zero = {0.f, 0.f, 0.f, 0.f};
#pragma unroll
  for (int i = 0; i < 8; ++i)
#pragma unroll
    for (int j = 0; j < 4; ++j) acc[i][j] = zero;

  bf16x8 ar[4][2], bc0[2][2], bc1[2][2];
  const int NT = g.K >> 6;

  gload16(bP[0], Bls + 0 * 8192 + ldst);
  gload16(bP[1], Bls + 1 * 8192 + ldst);
  gload16(aP[0], Als + 0 * 8192 + ldst);
  gload16(aP[1], Als + 1 * 8192 + ldst);
  gload16(bP[2], Bls + 2 * 8192 + ldst);
  gload16(bP[3], Bls + 3 * 8192 + ldst);
  gload16(aP[2], Als + 2 * 8192 + ldst);
  gload16(aP[3], Als + 3 * 8192 + ldst);
  waitv<4>();
  __builtin_amdgcn_s_barrier();

  for (int T = 0; T < NT; ++T) {
    const int buf = T & 1;
    const char* Ab = Als + buf * ABYTES;
    const char* Bb = Bls + buf * BBYTES;
    char* An = Als + (buf ^ 1) * ABYTES;
    char* Bn = Bls + (buf ^ 1) * BBYTES;
    const bool stg = (T + 1 < NT);
    const int kn = (T + 1) << 6;

    // ph0
#pragma unroll
    for (int f = 0; f < 4; ++f) {
      ar[f][0] = ldr(Ab + aRB0 + f * 2048 + slot0);
      ar[f][1] = ldr(Ab + aRB0 + f * 2048 + slot1);
    }
#pragma unroll
    for (int c = 0; c < 2; ++c) {
      bc0[c][0] = ldr(Bb + bCB0 + c * 2048 + slot0);
      bc0[c][1] = ldr(Bb + bCB0 + c * 2048 + slot1);
    }
    if (stg) {
      gload16(bP[0] + kn, Bn + 0 * 8192 + ldst);
      gload16(bP[1] + kn, Bn + 1 * 8192 + ldst);
    }
    __builtin_amdgcn_s_barrier();
    waitlgkm0();
    __builtin_amdgcn_s_setprio(1);
#pragma unroll
    for (int ksl = 0; ksl < 2; ++ksl)
#pragma unroll
      for (int f = 0; f < 4; ++f)
#pragma unroll
        for (int c = 0; c < 2; ++c)
          acc[f][c] = __builtin_amdgcn_mfma_f32_16x16x32_bf16(
              ar[f][ksl], bc0[c][ksl], acc[f][c], 0, 0, 0);
    __builtin_amdgcn_s_setprio(0);
    if (stg) waitv<4>(); else waitv<2>();
    __builtin_amdgcn_s_barrier();

    // ph1
#pragma unroll
    for (int c = 0; c < 2; ++c) {
      bc1[c][0] = ldr(Bb + bCB1 + c * 2048 + slot0);
      bc1[c][1] = ldr(Bb + bCB1 + c * 2048 + slot1);
    }
    if (stg) {
      gload16(aP[0] + kn, An + 0 * 8192 + ldst);
      gload16(aP[1] + kn, An + 1 * 8192 + ldst);
    }
    __builtin_amdgcn_s_barrier();
    waitlgkm0();
    __builtin_amdgcn_s_setprio(1);
#pragma unroll
    for (int ksl = 0; ksl < 2; ++ksl)
#pragma unroll
      for (int f = 0; f < 4; ++f)
#pragma unroll
        for (int c = 0; c < 2; ++c)
          acc[f][2 + c] = __builtin_amdgcn_mfma_f32_16x16x32_bf16(
              ar[f][ksl], bc1[c][ksl], acc[f][2 + c], 0, 0, 0);
    __builtin_amdgcn_s_setprio(0);
    if (stg) waitv<4>(); else waitv<0>();
    __builtin_amdgcn_s_barrier();

    // ph2
#pragma unroll
    for (int f = 0; f < 4; ++f) {
      ar[f][0] = ldr(Ab + aRB1 + f * 2048 + slot0);
      ar[f][1] = ldr(Ab + aRB1 + f * 2048 + slot1);
    }
    if (stg) {
      gload16(bP[2] + kn, Bn + 2 * 8192 + ldst);
      gload16(bP[3] + kn, Bn + 3 * 8192 + ldst);
    }
    __builtin_amdgcn_s_barrier();
    waitlgkm0();
    __builtin_amdgcn_s_setprio(1);
#pragma unroll
    for (int ksl = 0; ksl < 2; ++ksl)
#pragma unroll
      for (int f = 0; f < 4; ++f)
#pragma unroll
        for (int c = 0; c < 2; ++c)
          acc[4 + f][2 + c] = __builtin_amdgcn_mfma_f32_16x16x32_bf16(
              ar[f][ksl], bc1[c][ksl], acc[4 + f][2 + c], 0, 0, 0);
    __builtin_amdgcn_s_setprio(0);
    __builtin_amdgcn_s_barrier();

    // ph3
    if (stg) {
      gload16(aP[2] + kn, An + 2 * 8192 + ldst);
      gload16(aP[3] + kn, An + 3 * 8192 + ldst);
    }
    __builtin_amdgcn_s_barrier();
    __builtin_amdgcn_s_setprio(1);
#pragma unroll
    for (int ksl = 0; ksl < 2; ++ksl)
#pragma unroll
      for (int f = 0; f < 4; ++f)
#pragma unroll
        for (int c = 0; c < 2; ++c)
          acc[4 + f][c] = __builtin_amdgcn_mfma_f32_16x16x32_bf16(
              ar[f][ksl], bc0[c][ksl], acc[4 + f][c], 0, 0, 0);
    __builtin_amdgcn_s_setprio(0);
    if (stg) waitv<4>();
    __builtin_amdgcn_s_barrier();
  }

  const int rb = m0 + wm * 128 + (lg << 2);
  const int cb = n0 + wn * 64 + l15;
  const int N = g.N;
#pragma unroll
  for (int fg = 0; fg < 8; ++fg) {
#pragma unroll
    for (int j = 0; j < 4; ++j) {
      int col = cb + j * 16;
      float bv = g.bias[col];
#pragma unroll
      for (int r = 0; r < 4; ++r) {
        int row = rb + fg * 16 + r;
        float v = acc[fg][j][r] + bv;
        g.outb[(size_t)row * N + col] = f2bf(fmaxf(v, 0.f));
      }
    }
  }
}

// ---------------- gemmF: 128x256 tile, 2 fat phases (16 MFMA), 3-buf ring --
// Full-chip G2: grid 256 = 64bm x 4bn, K=4096. Gated accumulate epilogue.
// Per K-tile: 6 stage units (A0,A1,B0 | B1,B2,B3) for tile T+2; end-of-tile
// vmcnt(6) retires tile T+1's units (12 in flight -> 6). Never vmcnt(0) mid-loop.
__global__ __launch_bounds__(512)
void gemmF(const unsigned short* __restrict__ A,    // h [8192][4096] bf16
           const unsigned short* __restrict__ Bt,   // w2T [1024][4096] bf16
           const float* __restrict__ bias,          // eb2_e [1024]
           float* __restrict__ outC,
           const float* __restrict__ gates, int eidx, int accum) {
  constexpr int SLOT = 49152;  // 16KB A + 32KB B
  __shared__ char lds[3 * SLOT];
  const int t = threadIdx.x;
  const int lane = t & 63;
  const int wid = t >> 6;
  const int wm = wid >> 2;  // 0..1 -> rows wm*64
  const int wn = wid & 3;   // 0..3 -> cols wn*64
  const int l15 = lane & 15, lg = lane >> 4;

  // bijective XCD swizzle, 256 blocks
  const int local = blockIdx.x;
  const int swz = (local & 7) * 32 + (local >> 3);
  const int bn = swz & 3, bm = swz >> 2;  // bm 0..63
  const int m0 = bm * 128, n0 = bn * 256;

  // staging (XOR chunk swizzle, same involution as reads)
  const int prow = t >> 3;                      // 0..63
  const int cOff = ((t & 7) ^ (prow & 7)) * 8;  // k-elem offset
  const unsigned short* aP[2];
  const unsigned short* bP[4];
#pragma unroll
  for (int u = 0; u < 2; ++u)  // A identity mapping: unit u = rows u*64..u*64+63
    aP[u] = A + (size_t)(m0 + u * 64 + prow) * DHID + cOff;
#pragma unroll
  for (int u = 0; u < 4; ++u) {  // B mapping identical to gemmU (verified vs epilogue)
    int p = u * 64 + prow;
    int gb = ((p >> 5) & 3) * 64 + ((p >> 7) & 1) * 32 + (p & 31);
    bP[u] = Bt + (size_t)(n0 + gb) * DHID + cOff;
  }
  const int ldst = t * 16;

  // LDS read bases
  const int slot0 = ((lg) ^ (l15 & 7)) * 16;
  const int slot1 = ((4 + lg) ^ (l15 & 7)) * 16;
  const int aRB = (wm * 64 + l15) * 128;          // frag f: + f*2048
  const int bCB0 = 16384 + (wn * 32 + l15) * 128; // c 0,1: + c*2048
  const int bCB1 = 16384 + (128 + wn * 32 + l15) * 128;  // c 2,3

  f32x4 acc[4][4];
  const f32x4 zero = {0.f, 0.f, 0.f, 0.f};
#pragma unroll
  for (int i = 0; i < 4; ++i)
#pragma unroll
    for (int j = 0; j < 4; ++j) acc[i][j] = zero;

  bf16x8 af[2][2], bc[4][2];
  const int NT = DHID >> 6;  // 64

  // prologue: stage tiles 0,1 fully (6 units each); retire tile 0
#pragma unroll
  for (int T0 = 0; T0 < 2; ++T0) {
    char* S = lds + T0 * SLOT;
    const int k0 = T0 << 6;
    gload16(aP[0] + k0, S + 0 * 8192 + ldst);
    gload16(aP[1] + k0, S + 1 * 8192 + ldst);
    gload16(bP[0] + k0, S + 16384 + 0 * 8192 + ldst);
    gload16(bP[1] + k0, S + 16384 + 1 * 8192 + ldst);
    gload16(bP[2] + k0, S + 16384 + 2 * 8192 + ldst);
    gload16(bP[3] + k0, S + 16384 + 3 * 8192 + ldst);
  }
  waitv<6>();
  __builtin_amdgcn_s_barrier();

  for (int T = 0; T < NT; ++T) {
    const char* Sb = lds + (T % 3) * SLOT;
    char* Sn = lds + ((T + 2) % 3) * SLOT;
    const bool stg = (T + 2 < NT);
    const int kn = (T + 2) << 6;

    // ---- ph0: read A frags 0-1 + all B; stage A0,A1,B0; 16 MFMA ----
#pragma unroll
    for (int f = 0; f < 2; ++f) {
      af[f][0] = ldr(Sb + aRB + f * 2048 + slot0);
      af[f][1] = ldr(Sb + aRB + f * 2048 + slot1);
    }
#pragma unroll
    for (int c = 0; c < 2; ++c) {
      bc[c][0] = ldr(Sb + bCB0 + c * 2048 + slot0);
      bc[c][1] = ldr(Sb + bCB0 + c * 2048 + slot1);
      bc[2 + c][0] = ldr(Sb + bCB1 + c * 2048 + slot0);
      bc[2 + c][1] = ldr(Sb + bCB1 + c * 2048 + slot1);
    }
    if (stg) {
      gload16(aP[0] + kn, Sn + 0 * 8192 + ldst);
      gload16(aP[1] + kn, Sn + 1 * 8192 + ldst);
      gload16(bP[0] + kn, Sn + 16384 + 0 * 8192 + ldst);
    }
    __builtin_amdgcn_s_barrier();
    waitlgkm0();
    __builtin_amdgcn_s_setprio(1);
#pragma unroll
    for (int ksl = 0; ksl < 2; ++ksl)
#pragma unroll
      for (int f = 0; f < 2; ++f)
#pragma unroll
        for (int c = 0; c < 4; ++c)
          acc[f][c] = __builtin_amdgcn_mfma_f32_16x16x32_bf16(
              af[f][ksl], bc[c][ksl], acc[f][c], 0, 0, 0);
    __builtin_amdgcn_s_setprio(0);
    __builtin_amdgcn_s_barrier();

    // ---- ph1: read A frags 2-3; stage B1,B2,B3; 16 MFMA ----
#pragma unroll
    for (int f = 0; f < 2; ++f) {
      af[f][0] = ldr(Sb + aRB + (2 + f) * 2048 + slot0);
      af[f][1] = ldr(Sb + aRB + (2 + f) * 2048 + slot1);
    }
    if (stg) {
      gload16(bP[1] + kn, Sn + 16384 + 1 * 8192 + ldst);
      gload16(bP[2] + kn, Sn + 16384 + 2 * 8192 + ldst);
      gload16(bP[3] + kn, Sn + 16384 + 3 * 8192 + ldst);
    }
    __builtin_amdgcn_s_barrier();
    waitlgkm0();
    __builtin_amdgcn_s_setprio(1);
#pragma unroll
    for (int ksl = 0; ksl < 2; ++ksl)
#pragma unroll
      for (int f = 0; f < 2; ++f)
#pragma unroll
        for (int c = 0; c < 4; ++c)
          acc[2 + f][c] = __builtin_amdgcn_mfma_f32_16x16x32_bf16(
              af[f][ksl], bc[c][ksl], acc[2 + f][c], 0, 0, 0);
    __builtin_amdgcn_s_setprio(0);
    if (stg) waitv<6>();
    else if (T + 1 < NT) waitv<0>();
    __builtin_amdgcn_s_barrier();
  }

  // epilogue: gated accumulate (one writer per element per dispatch)
  const int rb = m0 + wm * 64 + (lg << 2);
  const int cb = n0 + wn * 64 + l15;
#pragma unroll
  for (int fg = 0; fg < 4; ++fg) {
    float gv[4];
#pragma unroll
    for (int r = 0; r < 4; ++r)
      gv[r] = gates[(size_t)(rb + fg * 16 + r) * NEXP + eidx];
#pragma unroll
    for (int j = 0; j < 4; ++j) {
      int col = cb + j * 16;
      float bv = bias[col];
#pragma unroll
      for (int r = 0; r < 4; ++r) {
        size_t o = (size_t)(rb + fg * 16 + r) * DOUT + col;
        float v = (acc[fg][j][r] + bv) * gv[r];
        outC[o] = accum ? outC[o] + v : v;
      }
    }
  }
}

// ---------------- gating head ----------------
__global__ __launch_bounds__(512)
void gating_head2(const unsigned short* __restrict__ gh,
                  const float* __restrict__ gW2,
                  const float* __restrict__ gb2,
                  float* __restrict__ gws,
                  float* __restrict__ g1,
                  float* __restrict__ g2) {
  __shared__ float wT[8][2048];
  const int t = threadIdx.x;
  for (int idx = t; idx < 16384; idx += 512) {
    wT[idx & 7][idx >> 3] = gW2[idx];
  }
  __syncthreads();
  const int wid = t >> 6, lane = t & 63;
  const int row = blockIdx.x * 8 + wid;
  const unsigned short* ghr = gh + (size_t)row * 2048;
  float s[8] = {0.f, 0.f, 0.f, 0.f, 0.f, 0.f, 0.f, 0.f};
#pragma unroll
  for (int j = 0; j < 8; ++j) {
    int k4 = lane + 64 * j;
    ushort4 hv = ((const ushort4*)ghr)[k4];
    float h0 = b2f(hv.x), h1 = b2f(hv.y), h2 = b2f(hv.z), h3 = b2f(hv.w);
#pragma unroll
    for (int e = 0; e < 8; ++e) {
      float4 w = ((const float4*)&wT[e][0])[k4];
      s[e] += h0 * w.x + h1 * w.y + h2 * w.z + h3 * w.w;
    }
  }
#pragma unroll
  for (int e = 0; e < 8; ++e)
#pragma unroll
    for (int off = 1; off < 64; off <<= 1) s[e] += __shfl_xor(s[e], off, 64);
  if (lane == 0) {
    float l[8], m = -1e30f;
#pragma unroll
    for (int e = 0; e < 8; ++e) {
      l[e] = s[e] + gb2[e];
      m = fmaxf(m, l[e]);
    }
    float sum = 0.f;
#pragma unroll
    for (int e = 0; e < 8; ++e) {
      l[e] = expf(l[e] - m);
      sum += l[e];
    }
    float inv = 1.f / sum;
#pragma unroll
    for (int e = 0; e < 8; ++e) {
      float gv = l[e] * inv;
      gws[(size_t)row * 8 + e] = gv;
      g1[(size_t)row * 8 + e] = gv;
      g2[(size_t)row * 8 + e] = gv;
    }
  }
}

extern "C" void kernel_launch(void* const* d_in, const int* in_sizes, int n_in,
                              void* d_out, int out_size, void* d_ws,
                              size_t ws_size, hipStream_t stream) {
  (void)in_sizes; (void)n_in; (void)out_size; (void)ws_size;
  const float* x   = (const float*)d_in[0];
  const float* gW1 = (const float*)d_in[1];
  const float* gb1 = (const float*)d_in[2];
  const float* gW2 = (const float*)d_in[3];
  const float* gb2 = (const float*)d_in[4];
  const float* eW1 = (const float*)d_in[5];
  const float* eb1 = (const float*)d_in[6];
  const float* eW2 = (const float*)d_in[7];
  const float* eb2 = (const float*)d_in[8];

  float* outC  = (float*)d_out;                       // [8192,1024]
  float* outG1 = outC + (size_t)BB * DOUT;            // [8192,8]
  float* outG2 = outG1 + (size_t)BB * NEXP;           // [8192,8]

  char* ws = (char*)d_ws;
  // layout: 100,925,440 B total
  unsigned short* xb   = (unsigned short*)(ws);                 // 16 MB
  float*          gat  = (float*)(ws + 16777216);               // 256 KB
  unsigned short* w1T  = (unsigned short*)(ws + 17039360);      // 8 MB
  unsigned short* w2T  = (unsigned short*)(ws + 25427968);      // 8 MB
  unsigned short* hbuf = (unsigned short*)(ws + 33816576);      // 64 MB
  unsigned short* gh   = hbuf;                  // pre-loop alias (32 MB)
  unsigned short* gW1T = w1T;                   // pre-loop alias (4 MB)

  // x -> bf16
  cvt_f32_bf16<<<(BB * DIN / 4) / 256, 256, 0, stream>>>(x, xb, BB * DIN / 4);
  // gW1 [1024][2048] -> gW1T [2048][1024] bf16
  transpose_cvt64<<<dim3(GH_N / 64, DIN / 64), 256, 0, stream>>>(gW1, gW1T, DIN, GH_N);
  // gating GEMM: gh = relu(x @ gW1 + gb1)   grid 256 (full chip)
  {
    GArgs a{xb, gW1T, DIN, DIN, GH_N, DIN, gb1, gh, 256};
    gemmU<<<256, 512, 0, stream>>>(a);
  }
  gating_head2<<<BB / 8, 512, 0, stream>>>(gh, gW2, gb2, gat, outG1, outG2);

  for (int e = 0; e < NEXP; ++e) {
    transpose_cvt2<<<2048, 256, 0, stream>>>(
        eW1 + (size_t)e * DIN * DHID, w1T, eW2 + (size_t)e * DHID * DOUT, w2T);
    // G1: h = relu(x @ eW1_e + eb1_e)   grid 512 (2 exact rounds)
    {
      GArgs a{xb, w1T, DIN, DIN, DHID, DIN, eb1 + (size_t)e * DHID, hbuf, 512};
      gemmU<<<512, 512, 0, stream>>>(a);
    }
    // G2: outC (+)= gat[:,e]*(h @ eW2_e + eb2_e)   grid 256 (full chip, fat)
    gemmF<<<256, 512, 0, stream>>>(hbuf, w2T, eb2 + (size_t)e * DOUT, outC,
                                   gat, e, e > 0 ? 1 : 0);
  }
}